// Round 11
// baseline (1113.738 us; speedup 1.0000x reference)
//
#include <hip/hip_runtime.h>
#include <stdint.h>

typedef unsigned short u16;
typedef unsigned char u8;
typedef unsigned int u32;
typedef short shortx8 __attribute__((ext_vector_type(8)));
typedef float floatx4 __attribute__((ext_vector_type(4)));
typedef int intx4 __attribute__((ext_vector_type(4)));
typedef int intx8 __attribute__((ext_vector_type(8)));

__device__ __forceinline__ u16 f2bf(float f) {
    u32 u = __builtin_bit_cast(u32, f);
    u = (u + 0x7fffu + ((u >> 16) & 1u)) >> 16;
    return (u16)u;
}

#if defined(__has_builtin)
#  if __has_builtin(__builtin_amdgcn_cvt_pk_fp8_f32)
#    define HAVE_CVT_FP8 1
#  endif
#  if __has_builtin(__builtin_amdgcn_global_load_lds)
#    define HAVE_GLL 1
#  endif
#endif
#ifndef HAVE_CVT_FP8
#  define HAVE_CVT_FP8 0
#endif
#ifndef HAVE_GLL
#  define HAVE_GLL 0
#endif

// fp32 -> OCP e4m3fn, RNE
__device__ __forceinline__ u8 f2fp8(float f) {
#if HAVE_CVT_FP8
    return (u8)(__builtin_amdgcn_cvt_pk_fp8_f32(f, f, 0, false) & 0xff);
#else
    u32 u = __builtin_bit_cast(u32, f);
    u32 s = (u >> 24) & 0x80u;
    u32 m = u & 0x7fffffffu;
    if (m >= 0x43e00000u) return (u8)(s | 0x7eu);
    if (m < 0x3c800000u) {
        int q = __float2int_rn(__builtin_bit_cast(float, m) * 512.f);
        return (u8)(s | (u32)q);
    }
    u32 r = m + 0x7ffffu + ((m >> 20) & 1u);
    u32 code = (((r >> 23) - 120u) << 3) | ((r >> 20) & 7u);
    if (code > 0x7eu) code = 0x7eu;
    return (u8)(s | code);
#endif
}

#if HAVE_GLL
__device__ __forceinline__ void gload_lds16(const void* g, void* l) {
    __builtin_amdgcn_global_load_lds(
        (const __attribute__((address_space(1))) u32*)g,
        (__attribute__((address_space(3))) u32*)l,
        16, 0, 0);
}
#endif

// ---------------------------------------------------------------------------
// bf16 GEMM: C[m,n] = sum_k A[m,k] * Bt[n,k]  (+ epilogue per MODE)
// A: (M,K) bf16 row-major lda; Bt: (N,K) bf16 row-major ldb. K % 64 == 0.
// 128x128 tile, BK=64, 4 waves 2x2, 4x4 16x16x32 MFMA, linear staging.
// MODE: 1 = +colbias aux[n]; OutT=u16 -> plain bf16 out,
//                            OutT=u8  -> fp8 out in TILED-SWIZZLED layout:
//                            tile (mb*16+nb) is 16KB contiguous; row r's 16B
//                            chunk c stored at r*128 + (c^(r&7))*16.
//       2 = +rowbias aux[m]; 4 = acc / aux[m] (fp32 out)
// SWZ=1: 1D grid, f&7 -> XCD: z = xcd>>1, n-half = xcd&1. 32 m-blocks req'd.
// ---------------------------------------------------------------------------
template <typename OutT, int MODE, int SWZ>
__global__ __launch_bounds__(256, 2) void gemm_bt(
    const u16* __restrict__ Ag, const u16* __restrict__ Bg, OutT* __restrict__ Cg,
    int lda, int ldb, int ldc, int K,
    const float* __restrict__ aux, float scale,
    long long sAz, long long sBz, long long sCz, long long sXz,
    int swz_nhalf)
{
    __shared__ u16 smem[4][128 * 32];   // 32 KB: A panels 0/1, B panels 0/1

    int z, mb, nb;
    if constexpr (SWZ) {
        const int f = blockIdx.x, xcd = f & 7, g = f >> 3;
        z = xcd >> 1;
        mb = g & 31;
        nb = (xcd & 1) * swz_nhalf + (g >> 5);
    } else {
        z = blockIdx.z; mb = blockIdx.y; nb = blockIdx.x;
    }
    const int m0 = mb * 128, n0 = nb * 128;

    const u16* A = Ag + (long long)z * sAz;
    const u16* B = Bg + (long long)z * sBz;
    OutT* C = Cg + (long long)z * sCz;
    const float* auxp = aux ? aux + (long long)z * sXz : nullptr;

    const int tid = threadIdx.x, lane = tid & 63, wv = tid >> 6;

    const int srow = lane >> 2;        // 0..15
    const int schunk = (lane & 3) * 8; // element offset of this lane's 16B
    const u16* gA0 = A + (size_t)(m0 + wv * 16 + srow) * lda + schunk;
    const u16* gA1 = gA0 + (size_t)64 * lda;
    const u16* gB0 = B + (size_t)(n0 + wv * 16 + srow) * ldb + schunk;
    const u16* gB1 = gB0 + (size_t)64 * ldb;
    const int wb = wv * 512;           // wave-uniform LDS base (u16 elems)

    const int wm = (wv & 1) * 64, wn = (wv >> 1) * 64;
    const int mi = lane & 15, kq = lane >> 4;

    floatx4 acc[4][4] = {};

    for (int k0 = 0; k0 < K; k0 += 64) {
#if HAVE_GLL
        gload_lds16(gA0,      &smem[0][wb]);
        gload_lds16(gA1,      &smem[0][2048 + wb]);
        gload_lds16(gA0 + 32, &smem[1][wb]);
        gload_lds16(gA1 + 32, &smem[1][2048 + wb]);
        gload_lds16(gB0,      &smem[2][wb]);
        gload_lds16(gB1,      &smem[2][2048 + wb]);
        gload_lds16(gB0 + 32, &smem[3][wb]);
        gload_lds16(gB1 + 32, &smem[3][2048 + wb]);
#else
        *(shortx8*)(&smem[0][wb] + lane * 8)        = *(const shortx8*)gA0;
        *(shortx8*)(&smem[0][2048 + wb] + lane * 8) = *(const shortx8*)gA1;
        *(shortx8*)(&smem[1][wb] + lane * 8)        = *(const shortx8*)(gA0 + 32);
        *(shortx8*)(&smem[1][2048 + wb] + lane * 8) = *(const shortx8*)(gA1 + 32);
        *(shortx8*)(&smem[2][wb] + lane * 8)        = *(const shortx8*)gB0;
        *(shortx8*)(&smem[2][2048 + wb] + lane * 8) = *(const shortx8*)gB1;
        *(shortx8*)(&smem[3][wb] + lane * 8)        = *(const shortx8*)(gB0 + 32);
        *(shortx8*)(&smem[3][2048 + wb] + lane * 8) = *(const shortx8*)(gB1 + 32);
#endif
        gA0 += 64; gA1 += 64; gB0 += 64; gB1 += 64;
        __syncthreads();

#pragma unroll
        for (int h = 0; h < 2; h++) {
            const u16* Ap = smem[h];
            const u16* Bp = smem[2 + h];
            shortx8 af[4], bfr[4];
#pragma unroll
            for (int i = 0; i < 4; i++)
                af[i] = *(const shortx8*)(Ap + (wm + i * 16 + mi) * 32 + kq * 8);
#pragma unroll
            for (int j = 0; j < 4; j++)
                bfr[j] = *(const shortx8*)(Bp + (wn + j * 16 + mi) * 32 + kq * 8);
#pragma unroll
            for (int i = 0; i < 4; i++)
#pragma unroll
                for (int j = 0; j < 4; j++)
                    acc[i][j] = __builtin_amdgcn_mfma_f32_16x16x32_bf16(
                        af[i], bfr[j], acc[i][j], 0, 0, 0);
        }
        __syncthreads();
    }

    // epilogue. C/D layout: col = lane&15, row = (lane>>4)*4 + reg.
    float cb[4];
    if constexpr (MODE == 1) {
#pragma unroll
        for (int j = 0; j < 4; j++) cb[j] = auxp[n0 + wn + j * 16 + mi];
    }

    if constexpr (sizeof(OutT) == 2) {
        u16* ct = &smem[0][0];
#pragma unroll
        for (int i = 0; i < 4; i++) {
#pragma unroll
            for (int r = 0; r < 4; r++) {
                const int lrow = wm + i * 16 + kq * 4 + r;
                float radd = 0.f;
                if constexpr (MODE == 2) radd = auxp[m0 + lrow];
#pragma unroll
                for (int j = 0; j < 4; j++) {
                    float v = acc[i][j][r];
                    if constexpr (MODE == 1) v += cb[j];
                    if constexpr (MODE == 2) v += radd;
                    ct[lrow * 128 + wn + j * 16 + mi] = f2bf(v);
                }
            }
        }
        __syncthreads();
#pragma unroll
        for (int it = 0; it < 8; it++) {
            const int fl = (it * 256 + tid) * 8;        // u16 elems
            const int row = fl >> 7, col = fl & 127;
            *(uint4*)(C + (size_t)(m0 + row) * ldc + n0 + col) =
                *(const uint4*)(ct + fl);
        }
    } else if constexpr (sizeof(OutT) == 1) {
        // fp8 tiled-swizzled output (MODE 1)
        u8* ct = (u8*)&smem[0][0];
#pragma unroll
        for (int i = 0; i < 4; i++) {
#pragma unroll
            for (int r = 0; r < 4; r++) {
                const int lrow = wm + i * 16 + kq * 4 + r;
#pragma unroll
                for (int j = 0; j < 4; j++) {
                    float v = acc[i][j][r];
                    if constexpr (MODE == 1) v += cb[j];
                    ct[lrow * 128 + wn + j * 16 + mi] = f2fp8(v);
                }
            }
        }
        __syncthreads();
        u8* base = (u8*)Cg + ((size_t)mb * 16 + nb) * 16384;
#pragma unroll
        for (int it = 0; it < 4; it++) {
            const int fl = (it * 256 + tid) * 16;       // bytes
            const int row = fl >> 7, c = (fl >> 4) & 7;
            *(uint4*)(base + row * 128 + ((c ^ (row & 7)) << 4)) =
                *(const uint4*)(ct + fl);
        }
    } else {
        // fp32 direct stores (MODE 4)
#pragma unroll
        for (int i = 0; i < 4; i++) {
#pragma unroll
            for (int r = 0; r < 4; r++) {
                const int row = m0 + wm + i * 16 + kq * 4 + r;
                float rmul = 1.f;
                if constexpr (MODE == 4) rmul = 1.0f / auxp[row];
                OutT* crow = C + (size_t)row * ldc;
#pragma unroll
                for (int j = 0; j < 4; j++) {
                    const int col = n0 + wn + j * 16 + mi;
                    crow[col] = acc[i][j][r] * rmul;
                }
            }
        }
    }
}

// ---------------------------------------------------------------------------
// R7: 256x256-tile PV GEMM: out[m,n] = (sum_k P[m,k] * Vt[n,k]) / sums[m].
// (Verified R4: left top-5, total 535->509.) bf16 MFMA puts acc in AGPRs, so
// the (512,2) 128-VGPR cap is fine here (128V + 128A at 1 blk/CU, LDS-bound).
// ---------------------------------------------------------------------------
__global__ __launch_bounds__(512, 2) void gemm_pv256(
    const u16* __restrict__ Pg, const u16* __restrict__ Vt,
    float* __restrict__ outg, const float* __restrict__ sums, int T, int NT)
{
    __shared__ u8 smem[2][65536];   // 128 KB: [slot][A 32KB | B 32KB]

    const int f = blockIdx.x, xcd = f & 7, g = f >> 3;
    const int z = xcd >> 1;
    const int nb = (xcd & 1) * 2 + (g >> 4);   // 0..3
    const int mb = g & 15;                     // 0..15
    const int m0 = mb * 256, n0 = nb * 256;

    const u8* Pz = (const u8*)(Pg + (size_t)z * T * T);
    const u8* Vz = (const u8*)(Vt + (size_t)z * T);   // col offset into Vt rows
    const float* sumz = sums + (size_t)z * T;

    const int tid = threadIdx.x, lane = tid & 63, wv = tid >> 6;
    const int wr = wv >> 2, wc = wv & 3;       // 2 x 4 wave grid
    const int mi = lane & 15, kq = lane >> 4;

    // staging: wave covers 8 regions of 1KB (8 rows x 8 chunks of 16B);
    // source chunk pre-swizzled so linear LDS holds chunk^(row&7) (rule #21).
    const int srow = lane >> 3;
    const int schunk = ((lane & 7) ^ srow) << 4;
    const size_t ldPb = (size_t)T * 2, ldVb = (size_t)NT * 2;
    const u8* gsrc;
    size_t grstride;
    int lds_r0;
    if (wv < 4) {
        gsrc = Pz + (size_t)(m0 + wv * 64 + srow) * ldPb + schunk;
        grstride = ldPb * 8;
        lds_r0 = wv * 8192;
    } else {
        gsrc = Vz + (size_t)(n0 + (wv - 4) * 64 + srow) * ldVb + schunk;
        grstride = ldVb * 8;
        lds_r0 = 32768 + (wv - 4) * 8192;
    }

    // reader swizzle: chunk(ks,kq) = ks*4+kq, row&7 = mi&7
    const int csw0 = ((0 * 4 + kq) ^ (mi & 7)) << 4;
    const int csw1 = ((1 * 4 + kq) ^ (mi & 7)) << 4;

    floatx4 acc[8][4] = {};

    auto stage = [&](int slot, int kt) {
        const u8* s0 = gsrc + (size_t)kt * 128;
        u8* l0 = &smem[slot][lds_r0];
#if HAVE_GLL
#pragma unroll
        for (int q = 0; q < 8; q++)
            gload_lds16(s0 + (size_t)q * grstride, l0 + q * 1024);
#else
#pragma unroll
        for (int q = 0; q < 8; q++)
            *(uint4*)(l0 + q * 1024 + lane * 16) =
                *(const uint4*)(s0 + (size_t)q * grstride);
#endif
    };

    stage(0, 0);
    __syncthreads();

    for (int kt = 0; kt < 64; kt++) {
        const int s = kt & 1;
        if (kt < 63) stage(s ^ 1, kt + 1);   // next tile's loads fly under compute
        __builtin_amdgcn_sched_barrier(0);   // pin: issue before ds_reads

        const u8* Ab = &smem[s][0];
        const u8* Bb = &smem[s][32768];

        shortx8 bfr[4][2];
#pragma unroll
        for (int nj = 0; nj < 4; nj++) {
            const u8* p = Bb + (wc * 64 + nj * 16 + mi) * 128;
            bfr[nj][0] = *(const shortx8*)(p + csw0);
            bfr[nj][1] = *(const shortx8*)(p + csw1);
        }
#pragma unroll
        for (int mh = 0; mh < 2; mh++) {
            shortx8 af[4][2];
#pragma unroll
            for (int fi = 0; fi < 4; fi++) {
                const u8* p = Ab + (wr * 128 + (mh * 4 + fi) * 16 + mi) * 128;
                af[fi][0] = *(const shortx8*)(p + csw0);
                af[fi][1] = *(const shortx8*)(p + csw1);
            }
            __builtin_amdgcn_s_setprio(1);
#pragma unroll
            for (int ks = 0; ks < 2; ks++)
#pragma unroll
                for (int fi = 0; fi < 4; fi++)
#pragma unroll
                    for (int nj = 0; nj < 4; nj++)
                        acc[mh * 4 + fi][nj] = __builtin_amdgcn_mfma_f32_16x16x32_bf16(
                            af[fi][ks], bfr[nj][ks], acc[mh * 4 + fi][nj], 0, 0, 0);
            __builtin_amdgcn_s_setprio(0);
        }
        __syncthreads();   // vmcnt(0) drain lands AFTER compute; publishes slot s^1
    }

    // epilogue: divide by row-sums, direct fp32 stores.
#pragma unroll
    for (int fr = 0; fr < 8; fr++) {
#pragma unroll
        for (int r = 0; r < 4; r++) {
            const int row = m0 + wr * 128 + fr * 16 + kq * 4 + r;
            const float rmul = 1.0f / sumz[row];
            float* crow = outg + ((size_t)z * T + row) * 1024 + n0 + wc * 64 + mi;
#pragma unroll
            for (int nj = 0; nj < 4; nj++)
                crow[nj * 16] = acc[fr][nj][r] * rmul;
        }
    }
}

__device__ __forceinline__ intx8 cat8(intx4 a, intx4 b) {
    return __builtin_shufflevector(a, b, 0, 1, 2, 3, 4, 5, 6, 7);
}

// ---------------------------------------------------------------------------
// Scores GEMM, MX-fp8 unit scales: P[m,n] = exp(scale * sum_k Q[m,k]K[n,k]).
// Input QKt: tiled-swizzled fp8, tile (tok_tile*16 + kp) is 16 KB contiguous,
// kp 0..7 = q panels, 8..15 = k panels; row r chunk c at r*128 + (c^(r&7))*16.
// BK=128, mfma_scale_f32_16x16x128_f8f6f4, fused row-sum atomics, bf16 P out.
//
// R14: 256x256-tile PV-style shape (rationale: per-barrier FLOP amortization;
// R13 refuted LDS conflicts, R9 refuted vmcnt depth, all pipes <=22%).
// R14 RAN BUT SPILLED: VGPR_Count pinned at exactly 128 with 2.3GB scratch
// round-trip (FETCH 1.5GB/WRITE 1.16GB), 760us. Decoded with R10's datum
// ((512,4)->64-cap): this compiler's launch_bounds 2nd arg ends up capping
// arch VGPRs at 512/(2*2nd-arg); (512,2) -> 128. pv256 survives that cap
// because bf16 v_mfma accumulates in AGPRs (128V+128A); the mfma_scale
// f8f6f4 variant keeps C/D in arch VGPRs -> needs ~220 -> spill.
// R15: THE ONE-TOKEN FIX — __launch_bounds__(512, 1): cap >=256 arch VGPRs,
// ~220 live fits, no spill. Occupancy is LDS-bound at 1 blk/CU regardless
// (128KB) — exactly pv256's proven operating point. Everything else is
// byte-identical to R14 (which passed correctness).
// Fallback (pre-committed): if scores >=137us, revert to R11 scores.
// ---------------------------------------------------------------------------
template <int SWZ>
__global__ __launch_bounds__(512, 1) void gemm_fp8_scores(
    const u8* __restrict__ QKt, u16* __restrict__ Pg,
    float* __restrict__ sums, float scale, int T)
{
    __shared__ u8 smem[2][65536];   // 128 KB: [buf][A 32KB | B 32KB]

    int z, mb, nb;                  // 256-tiles: mb,nb in [0,16)
    if constexpr (SWZ) {
        const int f = blockIdx.x, xcd = f & 7, g = f >> 3;   // f in [0,1024)
        z = xcd >> 1;
        mb = g & 15;
        nb = (xcd & 1) * 8 + (g >> 4);
    } else {
        z = blockIdx.z; mb = blockIdx.y; nb = blockIdx.x;
    }
    const int m0 = mb * 256, n0 = nb * 256;

    const u8* Aq0 = QKt + ((size_t)(z * 32 + 2 * mb) * 16) * 16384;        // q panels
    const u8* Aq1 = QKt + ((size_t)(z * 32 + 2 * mb + 1) * 16) * 16384;
    const u8* Bk0 = QKt + ((size_t)(z * 32 + 2 * nb) * 16 + 8) * 16384;    // k panels
    const u8* Bk1 = QKt + ((size_t)(z * 32 + 2 * nb + 1) * 16 + 8) * 16384;
    u16* P = Pg + (size_t)z * T * T;
    float* sumz = sums + (size_t)z * T;

    const int tid = threadIdx.x, lane = tid & 63, wv = tid >> 6;  // wv 0..7
    const int wr = wv >> 2, wc = wv & 3;          // 2 x 4 wave grid
    const int mi = lane & 15, kq = lane >> 4;
    const int xm = mi & 7;
    const int off0 = ((2 * kq) ^ xm) * 16;        // swizzled chunk offsets
    const int off1 = ((2 * kq + 1) ^ xm) * 16;

    // staging: each wave stages 8KB/panel (8 x 1KB contiguous, 16B/lane).
    // waves 0-3 -> A (tile-half th = w>>1, row-half rh = w&1);
    // waves 4-7 -> B likewise.
    const u8* gsrc;
    int ldst;
    {
        const int w = wv & 3, th = w >> 1, rh = w & 1;
        if (wv < 4) {
            gsrc = (th ? Aq1 : Aq0) + rh * 8192 + lane * 16;
            ldst = th * 16384 + rh * 8192;
        } else {
            gsrc = (th ? Bk1 : Bk0) + rh * 8192 + lane * 16;
            ldst = 32768 + th * 16384 + rh * 8192;
        }
    }

    floatx4 acc[8][4] = {};

    auto stageP = [&](int b) {
#if HAVE_GLL
#pragma unroll
        for (int i = 0; i < 8; i++)
            gload_lds16(gsrc + i * 1024, &smem[b][ldst + i * 1024]);
#else
#pragma unroll
        for (int i = 0; i < 8; i++)
            *(uint4*)(&smem[b][ldst + i * 1024] + lane * 16) =
                *(const uint4*)(gsrc + i * 1024);
#endif
        gsrc += 16384;
    };

    stageP(0);
    __syncthreads();

    for (int kp = 0; kp < 8; kp++) {
        const int cur = kp & 1;
        if (kp < 7) stageP(cur ^ 1);        // next panel flies under compute
        __builtin_amdgcn_sched_barrier(0);  // pin: staging issues before ds_reads

        const u8* Ab = &smem[cur][0] + wr * 16384;
        const u8* Bb = &smem[cur][32768] + (wc >> 1) * 16384;
        intx8 bfr[4];
#pragma unroll
        for (int j = 0; j < 4; j++) {
            const u8* p = Bb + ((wc & 1) * 64 + j * 16 + mi) * 128;
            bfr[j] = cat8(*(const intx4*)(p + off0), *(const intx4*)(p + off1));
        }
#pragma unroll
        for (int mh = 0; mh < 2; mh++) {
            intx8 af[4];
#pragma unroll
            for (int fi = 0; fi < 4; fi++) {
                const u8* p = Ab + ((mh * 4 + fi) * 16 + mi) * 128;
                af[fi] = cat8(*(const intx4*)(p + off0), *(const intx4*)(p + off1));
            }
            __builtin_amdgcn_s_setprio(1);
#pragma unroll
            for (int fi = 0; fi < 4; fi++)
#pragma unroll
                for (int j = 0; j < 4; j++)
                    acc[mh * 4 + fi][j] = __builtin_amdgcn_mfma_scale_f32_16x16x128_f8f6f4(
                        af[fi], bfr[j], acc[mh * 4 + fi][j], 0, 0,
                        0, 0x7f7f7f7f, 0, 0x7f7f7f7f);   // unit E8M0 scales
            __builtin_amdgcn_s_setprio(0);
        }
        __syncthreads();   // publishes buf cur^1; fences reads of cur
    }

    // epilogue: exp, bf16 P via full-LDS (256x256 u16 = 128KB), fused row-sum.
    // Safe: loop's final barrier passed, no loads outstanding, all of smem free.
    u16* ct = (u16*)&smem[0][0];
#pragma unroll
    for (int fr = 0; fr < 8; fr++) {
#pragma unroll
        for (int r = 0; r < 4; r++) {
            const int lrow = wr * 128 + fr * 16 + kq * 4 + r;
            float rs = 0.f;
#pragma unroll
            for (int j = 0; j < 4; j++) {
                float v = __expf(acc[fr][j][r] * scale);
                rs += v;
                ct[lrow * 256 + wc * 64 + j * 16 + mi] = f2bf(v);
            }
            rs += __shfl_xor(rs, 1);
            rs += __shfl_xor(rs, 2);
            rs += __shfl_xor(rs, 4);
            rs += __shfl_xor(rs, 8);
            if (mi == 0) atomicAdd(&sumz[m0 + lrow], rs);
        }
    }
    __syncthreads();
#pragma unroll
    for (int it = 0; it < 16; it++) {
        const int fl = (it * 512 + tid) * 8;            // u16 elems
        const int row = fl >> 8, col = fl & 255;
        *(uint4*)(P + (size_t)(m0 + row) * T + n0 + col) = *(const uint4*)(ct + fl);
    }
}

// fp32 -> bf16, 8 elements per thread
__global__ __launch_bounds__(256) void cvt_bf16(const float* __restrict__ s,
                                                u16* __restrict__ d, int n8)
{
    int i = blockIdx.x * 256 + threadIdx.x;
    if (i >= n8) return;
    const float4* sp = (const float4*)s;
    float4 a = sp[2 * i], b = sp[2 * i + 1];
    uint4 o;
    o.x = (u32)f2bf(a.x) | ((u32)f2bf(a.y) << 16);
    o.y = (u32)f2bf(a.z) | ((u32)f2bf(a.w) << 16);
    o.z = (u32)f2bf(b.x) | ((u32)f2bf(b.y) << 16);
    o.w = (u32)f2bf(b.z) | ((u32)f2bf(b.w) << 16);
    *(uint4*)(d + 8 * i) = o;
}

__global__ void concat2(const float* __restrict__ a, const float* __restrict__ b,
                        float* __restrict__ d, int n)
{
    int i = blockIdx.x * 256 + threadIdx.x;
    if (i < n) d[i] = a[i];
    else if (i < 2 * n) d[i] = b[i - n];
}

extern "C" void kernel_launch(void* const* d_in, const int* in_sizes, int n_in,
                              void* d_out, int out_size, void* d_ws, size_t ws_size,
                              hipStream_t stream)
{
    const float* X  = (const float*)d_in[0];
    const float* Wq = (const float*)d_in[1];
    const float* bq = (const float*)d_in[2];
    const float* Wk = (const float*)d_in[3];
    const float* bk = (const float*)d_in[4];
    const float* Wv = (const float*)d_in[5];
    const float* bv = (const float*)d_in[6];
    float* out = (float*)d_out;

    const int T = 4096, NT = 4 * T; // 16384 tokens
    const long long TL = T;

    char* ws = (char*)d_ws;
    size_t off = 0;
    auto alloc = [&](size_t bytes) {
        char* p = ws + off;
        off += (bytes + 255) & ~(size_t)255;
        return p;
    };
    u16*   Wqk  = (u16*)alloc((size_t)2048 * 1024 * 2);
    u16*   Wvb  = (u16*)alloc((size_t)1024 * 1024 * 2);
    float* bqk  = (float*)alloc(2048 * 4);
    u8*    QKt  = (u8*)alloc((size_t)128 * 16 * 16384);   // fp8 tiled q|k, 32 MB
    u16*   Vt   = (u16*)alloc((size_t)1024 * NT * 2);     // V^T bf16: [v][token]
    float* sums = (float*)alloc((size_t)NT * 4);          // softmax denominators
    size_t pbase = off;
    u16*   Xb   = (u16*)alloc((size_t)NT * 1024 * 2);     // X bf16; later reused as P
    u16*   P    = Xb;

    const size_t need_batched = pbase + (size_t)4 * T * T * 2;
    const bool batched = ws_size >= need_batched;

    // --- convert inputs to bf16 ---
    cvt_bf16<<<dim3((NT * 1024 / 8 + 255) / 256), dim3(256), 0, stream>>>(X, Xb, NT * 1024 / 8);
    cvt_bf16<<<dim3(512), dim3(256), 0, stream>>>(Wq, Wqk, 1024 * 1024 / 8);
    cvt_bf16<<<dim3(512), dim3(256), 0, stream>>>(Wk, Wqk + 1024 * 1024, 1024 * 1024 / 8);
    cvt_bf16<<<dim3(512), dim3(256), 0, stream>>>(Wv, Wvb, 1024 * 1024 / 8);
    concat2<<<dim3(8), dim3(256), 0, stream>>>(bq, bk, bqk, 1024);
    hipMemsetAsync(sums, 0, (size_t)NT * 4, stream);

    // --- QK(fp8, tiled) = X * [Wq;Wk]^T + bqk : M=16384, N=2048, K=1024 ---
    gemm_bt<u8, 1, 0><<<dim3(16, 128, 1), dim3(256), 0, stream>>>(
        Xb, Wqk, QKt, 1024, 1024, 0, 1024, bqk, 0.f, 0, 0, 0, 0, 0);

    // --- V^T = Wv * X^T + bv(row) : M=1024, N=16384, K=1024 ---
    gemm_bt<u16, 2, 0><<<dim3(128, 8, 1), dim3(256), 0, stream>>>(
        Wvb, Xb, Vt, 1024, 1024, NT, 1024, bv, 0.f, 0, 0, 0, 0, 0);

    if (batched) {
        // P~ = exp(Q K^T / 32), fused row-sums; 256^2-tile PV-style kernel
        gemm_fp8_scores<1><<<dim3(1024), dim3(512), 0, stream>>>(
            QKt, P, sums, 0.03125f, T);
        // out = (P~ * V) / sums ; 256^2-tile deep-pipelined kernel, 1 blk/CU
        gemm_pv256<<<dim3(256), dim3(512), 0, stream>>>(
            P, Vt, out, sums, T, NT);
    } else {
        for (int z = 0; z < 4; z++) {
            gemm_fp8_scores<0><<<dim3(16, 16, 1), dim3(512), 0, stream>>>(
                QKt + (size_t)z * 32 * 16 * 16384, P, sums + (size_t)z * T, 0.03125f, T);
            gemm_bt<float, 4, 0><<<dim3(8, 32, 1), dim3(256), 0, stream>>>(
                P, Vt + (size_t)z * T, out + (size_t)z * T * 1024,
                T, NT, 1024, T, sums + (size_t)z * T, 0.f, 0, 0, 0, 0, 0);
        }
    }
    (void)in_sizes; (void)n_in; (void)out_size;
}

// Round 12
// 469.692 us; speedup vs baseline: 2.3712x; 2.3712x over previous
//
#include <hip/hip_runtime.h>
#include <stdint.h>

typedef unsigned short u16;
typedef unsigned char u8;
typedef unsigned int u32;
typedef short shortx8 __attribute__((ext_vector_type(8)));
typedef float floatx4 __attribute__((ext_vector_type(4)));
typedef int intx4 __attribute__((ext_vector_type(4)));
typedef int intx8 __attribute__((ext_vector_type(8)));

__device__ __forceinline__ u16 f2bf(float f) {
    u32 u = __builtin_bit_cast(u32, f);
    u = (u + 0x7fffu + ((u >> 16) & 1u)) >> 16;
    return (u16)u;
}

#if defined(__has_builtin)
#  if __has_builtin(__builtin_amdgcn_cvt_pk_fp8_f32)
#    define HAVE_CVT_FP8 1
#  endif
#  if __has_builtin(__builtin_amdgcn_global_load_lds)
#    define HAVE_GLL 1
#  endif
#endif
#ifndef HAVE_CVT_FP8
#  define HAVE_CVT_FP8 0
#endif
#ifndef HAVE_GLL
#  define HAVE_GLL 0
#endif

// fp32 -> OCP e4m3fn, RNE
__device__ __forceinline__ u8 f2fp8(float f) {
#if HAVE_CVT_FP8
    return (u8)(__builtin_amdgcn_cvt_pk_fp8_f32(f, f, 0, false) & 0xff);
#else
    u32 u = __builtin_bit_cast(u32, f);
    u32 s = (u >> 24) & 0x80u;
    u32 m = u & 0x7fffffffu;
    if (m >= 0x43e00000u) return (u8)(s | 0x7eu);
    if (m < 0x3c800000u) {
        int q = __float2int_rn(__builtin_bit_cast(float, m) * 512.f);
        return (u8)(s | (u32)q);
    }
    u32 r = m + 0x7ffffu + ((m >> 20) & 1u);
    u32 code = (((r >> 23) - 120u) << 3) | ((r >> 20) & 7u);
    if (code > 0x7eu) code = 0x7eu;
    return (u8)(s | code);
#endif
}

#if HAVE_GLL
__device__ __forceinline__ void gload_lds16(const void* g, void* l) {
    __builtin_amdgcn_global_load_lds(
        (const __attribute__((address_space(1))) u32*)g,
        (__attribute__((address_space(3))) u32*)l,
        16, 0, 0);
}
#endif

// ---------------------------------------------------------------------------
// bf16 GEMM: C[m,n] = sum_k A[m,k] * Bt[n,k]  (+ epilogue per MODE)
// A: (M,K) bf16 row-major lda; Bt: (N,K) bf16 row-major ldb. K % 64 == 0.
// 128x128 tile, BK=64, 4 waves 2x2, 4x4 16x16x32 MFMA, linear staging.
// MODE: 1 = +colbias aux[n]; OutT=u16 -> plain bf16 out,
//                            OutT=u8  -> fp8 out in TILED-SWIZZLED layout:
//                            tile (mb*16+nb) is 16KB contiguous; row r's 16B
//                            chunk c stored at r*128 + (c^(r&7))*16.
//       2 = +rowbias aux[m]; 4 = acc / aux[m] (fp32 out)
// SWZ=1: 1D grid, f&7 -> XCD: z = xcd>>1, n-half = xcd&1. 32 m-blocks req'd.
// ---------------------------------------------------------------------------
template <typename OutT, int MODE, int SWZ>
__global__ __launch_bounds__(256, 2) void gemm_bt(
    const u16* __restrict__ Ag, const u16* __restrict__ Bg, OutT* __restrict__ Cg,
    int lda, int ldb, int ldc, int K,
    const float* __restrict__ aux, float scale,
    long long sAz, long long sBz, long long sCz, long long sXz,
    int swz_nhalf)
{
    __shared__ u16 smem[4][128 * 32];   // 32 KB: A panels 0/1, B panels 0/1

    int z, mb, nb;
    if constexpr (SWZ) {
        const int f = blockIdx.x, xcd = f & 7, g = f >> 3;
        z = xcd >> 1;
        mb = g & 31;
        nb = (xcd & 1) * swz_nhalf + (g >> 5);
    } else {
        z = blockIdx.z; mb = blockIdx.y; nb = blockIdx.x;
    }
    const int m0 = mb * 128, n0 = nb * 128;

    const u16* A = Ag + (long long)z * sAz;
    const u16* B = Bg + (long long)z * sBz;
    OutT* C = Cg + (long long)z * sCz;
    const float* auxp = aux ? aux + (long long)z * sXz : nullptr;

    const int tid = threadIdx.x, lane = tid & 63, wv = tid >> 6;

    const int srow = lane >> 2;        // 0..15
    const int schunk = (lane & 3) * 8; // element offset of this lane's 16B
    const u16* gA0 = A + (size_t)(m0 + wv * 16 + srow) * lda + schunk;
    const u16* gA1 = gA0 + (size_t)64 * lda;
    const u16* gB0 = B + (size_t)(n0 + wv * 16 + srow) * ldb + schunk;
    const u16* gB1 = gB0 + (size_t)64 * ldb;
    const int wb = wv * 512;           // wave-uniform LDS base (u16 elems)

    const int wm = (wv & 1) * 64, wn = (wv >> 1) * 64;
    const int mi = lane & 15, kq = lane >> 4;

    floatx4 acc[4][4] = {};

    for (int k0 = 0; k0 < K; k0 += 64) {
#if HAVE_GLL
        gload_lds16(gA0,      &smem[0][wb]);
        gload_lds16(gA1,      &smem[0][2048 + wb]);
        gload_lds16(gA0 + 32, &smem[1][wb]);
        gload_lds16(gA1 + 32, &smem[1][2048 + wb]);
        gload_lds16(gB0,      &smem[2][wb]);
        gload_lds16(gB1,      &smem[2][2048 + wb]);
        gload_lds16(gB0 + 32, &smem[3][wb]);
        gload_lds16(gB1 + 32, &smem[3][2048 + wb]);
#else
        *(shortx8*)(&smem[0][wb] + lane * 8)        = *(const shortx8*)gA0;
        *(shortx8*)(&smem[0][2048 + wb] + lane * 8) = *(const shortx8*)gA1;
        *(shortx8*)(&smem[1][wb] + lane * 8)        = *(const shortx8*)(gA0 + 32);
        *(shortx8*)(&smem[1][2048 + wb] + lane * 8) = *(const shortx8*)(gA1 + 32);
        *(shortx8*)(&smem[2][wb] + lane * 8)        = *(const shortx8*)gB0;
        *(shortx8*)(&smem[2][2048 + wb] + lane * 8) = *(const shortx8*)gB1;
        *(shortx8*)(&smem[3][wb] + lane * 8)        = *(const shortx8*)(gB0 + 32);
        *(shortx8*)(&smem[3][2048 + wb] + lane * 8) = *(const shortx8*)(gB1 + 32);
#endif
        gA0 += 64; gA1 += 64; gB0 += 64; gB1 += 64;
        __syncthreads();

#pragma unroll
        for (int h = 0; h < 2; h++) {
            const u16* Ap = smem[h];
            const u16* Bp = smem[2 + h];
            shortx8 af[4], bfr[4];
#pragma unroll
            for (int i = 0; i < 4; i++)
                af[i] = *(const shortx8*)(Ap + (wm + i * 16 + mi) * 32 + kq * 8);
#pragma unroll
            for (int j = 0; j < 4; j++)
                bfr[j] = *(const shortx8*)(Bp + (wn + j * 16 + mi) * 32 + kq * 8);
#pragma unroll
            for (int i = 0; i < 4; i++)
#pragma unroll
                for (int j = 0; j < 4; j++)
                    acc[i][j] = __builtin_amdgcn_mfma_f32_16x16x32_bf16(
                        af[i], bfr[j], acc[i][j], 0, 0, 0);
        }
        __syncthreads();
    }

    // epilogue. C/D layout: col = lane&15, row = (lane>>4)*4 + reg.
    float cb[4];
    if constexpr (MODE == 1) {
#pragma unroll
        for (int j = 0; j < 4; j++) cb[j] = auxp[n0 + wn + j * 16 + mi];
    }

    if constexpr (sizeof(OutT) == 2) {
        u16* ct = &smem[0][0];
#pragma unroll
        for (int i = 0; i < 4; i++) {
#pragma unroll
            for (int r = 0; r < 4; r++) {
                const int lrow = wm + i * 16 + kq * 4 + r;
                float radd = 0.f;
                if constexpr (MODE == 2) radd = auxp[m0 + lrow];
#pragma unroll
                for (int j = 0; j < 4; j++) {
                    float v = acc[i][j][r];
                    if constexpr (MODE == 1) v += cb[j];
                    if constexpr (MODE == 2) v += radd;
                    ct[lrow * 128 + wn + j * 16 + mi] = f2bf(v);
                }
            }
        }
        __syncthreads();
#pragma unroll
        for (int it = 0; it < 8; it++) {
            const int fl = (it * 256 + tid) * 8;        // u16 elems
            const int row = fl >> 7, col = fl & 127;
            *(uint4*)(C + (size_t)(m0 + row) * ldc + n0 + col) =
                *(const uint4*)(ct + fl);
        }
    } else if constexpr (sizeof(OutT) == 1) {
        // fp8 tiled-swizzled output (MODE 1)
        u8* ct = (u8*)&smem[0][0];
#pragma unroll
        for (int i = 0; i < 4; i++) {
#pragma unroll
            for (int r = 0; r < 4; r++) {
                const int lrow = wm + i * 16 + kq * 4 + r;
#pragma unroll
                for (int j = 0; j < 4; j++) {
                    float v = acc[i][j][r];
                    if constexpr (MODE == 1) v += cb[j];
                    ct[lrow * 128 + wn + j * 16 + mi] = f2fp8(v);
                }
            }
        }
        __syncthreads();
        u8* base = (u8*)Cg + ((size_t)mb * 16 + nb) * 16384;
#pragma unroll
        for (int it = 0; it < 4; it++) {
            const int fl = (it * 256 + tid) * 16;       // bytes
            const int row = fl >> 7, c = (fl >> 4) & 7;
            *(uint4*)(base + row * 128 + ((c ^ (row & 7)) << 4)) =
                *(const uint4*)(ct + fl);
        }
    } else {
        // fp32 direct stores (MODE 4)
#pragma unroll
        for (int i = 0; i < 4; i++) {
#pragma unroll
            for (int r = 0; r < 4; r++) {
                const int row = m0 + wm + i * 16 + kq * 4 + r;
                float rmul = 1.f;
                if constexpr (MODE == 4) rmul = 1.0f / auxp[row];
                OutT* crow = C + (size_t)row * ldc;
#pragma unroll
                for (int j = 0; j < 4; j++) {
                    const int col = n0 + wn + j * 16 + mi;
                    crow[col] = acc[i][j][r] * rmul;
                }
            }
        }
    }
}

// ---------------------------------------------------------------------------
// R7: 256x256-tile PV GEMM: out[m,n] = (sum_k P[m,k] * Vt[n,k]) / sums[m].
// (Verified R4: left top-5, total 535->509.) bf16 MFMA accumulates in AGPRs,
// so the (512,2) 128-VGPR arch cap is fine here (128V + 128A, 1 blk/CU).
// NOTE (R14/R15 lesson): do NOT port this geometry to mfma_scale f8f6f4 —
// that variant keeps C/D in arch VGPRs and spills catastrophically.
// ---------------------------------------------------------------------------
__global__ __launch_bounds__(512, 2) void gemm_pv256(
    const u16* __restrict__ Pg, const u16* __restrict__ Vt,
    float* __restrict__ outg, const float* __restrict__ sums, int T, int NT)
{
    __shared__ u8 smem[2][65536];   // 128 KB: [slot][A 32KB | B 32KB]

    const int f = blockIdx.x, xcd = f & 7, g = f >> 3;
    const int z = xcd >> 1;
    const int nb = (xcd & 1) * 2 + (g >> 4);   // 0..3
    const int mb = g & 15;                     // 0..15
    const int m0 = mb * 256, n0 = nb * 256;

    const u8* Pz = (const u8*)(Pg + (size_t)z * T * T);
    const u8* Vz = (const u8*)(Vt + (size_t)z * T);   // col offset into Vt rows
    const float* sumz = sums + (size_t)z * T;

    const int tid = threadIdx.x, lane = tid & 63, wv = tid >> 6;
    const int wr = wv >> 2, wc = wv & 3;       // 2 x 4 wave grid
    const int mi = lane & 15, kq = lane >> 4;

    // staging: wave covers 8 regions of 1KB (8 rows x 8 chunks of 16B);
    // source chunk pre-swizzled so linear LDS holds chunk^(row&7) (rule #21).
    const int srow = lane >> 3;
    const int schunk = ((lane & 7) ^ srow) << 4;
    const size_t ldPb = (size_t)T * 2, ldVb = (size_t)NT * 2;
    const u8* gsrc;
    size_t grstride;
    int lds_r0;
    if (wv < 4) {
        gsrc = Pz + (size_t)(m0 + wv * 64 + srow) * ldPb + schunk;
        grstride = ldPb * 8;
        lds_r0 = wv * 8192;
    } else {
        gsrc = Vz + (size_t)(n0 + (wv - 4) * 64 + srow) * ldVb + schunk;
        grstride = ldVb * 8;
        lds_r0 = 32768 + (wv - 4) * 8192;
    }

    // reader swizzle: chunk(ks,kq) = ks*4+kq, row&7 = mi&7
    const int csw0 = ((0 * 4 + kq) ^ (mi & 7)) << 4;
    const int csw1 = ((1 * 4 + kq) ^ (mi & 7)) << 4;

    floatx4 acc[8][4] = {};

    auto stage = [&](int slot, int kt) {
        const u8* s0 = gsrc + (size_t)kt * 128;
        u8* l0 = &smem[slot][lds_r0];
#if HAVE_GLL
#pragma unroll
        for (int q = 0; q < 8; q++)
            gload_lds16(s0 + (size_t)q * grstride, l0 + q * 1024);
#else
#pragma unroll
        for (int q = 0; q < 8; q++)
            *(uint4*)(l0 + q * 1024 + lane * 16) =
                *(const uint4*)(s0 + (size_t)q * grstride);
#endif
    };

    stage(0, 0);
    __syncthreads();

    for (int kt = 0; kt < 64; kt++) {
        const int s = kt & 1;
        if (kt < 63) stage(s ^ 1, kt + 1);   // next tile's loads fly under compute
        __builtin_amdgcn_sched_barrier(0);   // pin: issue before ds_reads

        const u8* Ab = &smem[s][0];
        const u8* Bb = &smem[s][32768];

        shortx8 bfr[4][2];
#pragma unroll
        for (int nj = 0; nj < 4; nj++) {
            const u8* p = Bb + (wc * 64 + nj * 16 + mi) * 128;
            bfr[nj][0] = *(const shortx8*)(p + csw0);
            bfr[nj][1] = *(const shortx8*)(p + csw1);
        }
#pragma unroll
        for (int mh = 0; mh < 2; mh++) {
            shortx8 af[4][2];
#pragma unroll
            for (int fi = 0; fi < 4; fi++) {
                const u8* p = Ab + (wr * 128 + (mh * 4 + fi) * 16 + mi) * 128;
                af[fi][0] = *(const shortx8*)(p + csw0);
                af[fi][1] = *(const shortx8*)(p + csw1);
            }
            __builtin_amdgcn_s_setprio(1);
#pragma unroll
            for (int ks = 0; ks < 2; ks++)
#pragma unroll
                for (int fi = 0; fi < 4; fi++)
#pragma unroll
                    for (int nj = 0; nj < 4; nj++)
                        acc[mh * 4 + fi][nj] = __builtin_amdgcn_mfma_f32_16x16x32_bf16(
                            af[fi][ks], bfr[nj][ks], acc[mh * 4 + fi][nj], 0, 0, 0);
            __builtin_amdgcn_s_setprio(0);
        }
        __syncthreads();   // vmcnt(0) drain lands AFTER compute; publishes slot s^1
    }

    // epilogue: divide by row-sums, direct fp32 stores.
#pragma unroll
    for (int fr = 0; fr < 8; fr++) {
#pragma unroll
        for (int r = 0; r < 4; r++) {
            const int row = m0 + wr * 128 + fr * 16 + kq * 4 + r;
            const float rmul = 1.0f / sumz[row];
            float* crow = outg + ((size_t)z * T + row) * 1024 + n0 + wc * 64 + mi;
#pragma unroll
            for (int nj = 0; nj < 4; nj++)
                crow[nj * 16] = acc[fr][nj][r] * rmul;
        }
    }
}

__device__ __forceinline__ intx8 cat8(intx4 a, intx4 b) {
    return __builtin_shufflevector(a, b, 0, 1, 2, 3, 4, 5, 6, 7);
}

// ---------------------------------------------------------------------------
// Scores GEMM, MX-fp8 unit scales: P[m,n] = exp(scale * sum_k Q[m,k]K[n,k]).
// Input QKt: tiled-swizzled fp8, tile (tok_tile*16 + kp) is 16 KB contiguous,
// kp 0..7 = q panels, 8..15 = k panels; row r chunk c at r*128 + (c^(r&7))*16.
// BK=128, mfma_scale_f32_16x16x128_f8f6f4, fused row-sum atomics, bf16 P out.
//
// R16: REVERT to the R11 configuration (the session's best: 475.8us total,
// scores 137us, VGPR 88, no spill). Post-mortem chain on this dispatch:
//   R9  counted-vmcnt depth-3: NULL (1 wave/SIMD, no TLP to overlap).
//   R10 8-wave TLP: mechanism confirmed (occ 11->43%) but (512,4) -> 64-VGPR
//       cap -> spill. R11 (512,2): fixed, 137us. Occupancy 2x gave only 12%.
//   R13 A-from-global: fewer bank conflicts but SLOWER (155us) - LDS
//       conflicts refuted as binder; scattered 16B reads amplify L2 traffic.
//   R14/R15 256^2 tile (PV shape): mfma_scale f8f6f4 keeps its 128-float acc
//       in ARCH VGPRs (bf16 v_mfma uses AGPRs); compiler pins 128 VGPRs
//       regardless of launch_bounds (2nd arg (512,2)->128 cap, (512,1) did
//       NOT lift it) -> 2.3GB scratch round-trip, 760-800us. Dead end on
//       this compiler. Pre-committed fallback executed: revert to R11.
// The residual ~137us (all pipes <=22%) is per-barrier sync overhead at
// 8 MFMA/wave/barrier; raising FLOP/barrier requires an acc that stays in
// registers, which this MFMA variant does not permit at the needed size.
// ---------------------------------------------------------------------------
template <int SWZ>
__global__ __launch_bounds__(512, 2) void gemm_fp8_scores(
    const u8* __restrict__ QKt, u16* __restrict__ Pg,
    float* __restrict__ sums, float scale, int T)
{
    __shared__ u8 smem[2][32768];   // 64 KB: buffer = [A 16K | B 16K]

    int z, mb, nb;
    if constexpr (SWZ) {
        const int f = blockIdx.x, xcd = f & 7, g = f >> 3;
        z = xcd >> 1;
        // super-tiled walk: 4 super-rows of (8 mb x 16 nb) per XCD
        const int s = g >> 7, t = g & 127;
        mb = (s << 3) | (t & 7);
        nb = (xcd & 1) * 16 + (t >> 3);
    } else {
        z = blockIdx.z; mb = blockIdx.y; nb = blockIdx.x;
    }
    const int m0 = mb * 128, n0 = nb * 128;

    const u8* At = QKt + ((size_t)(z * 32 + mb) * 16) * 16384;       // q panels
    const u8* Bt = QKt + ((size_t)(z * 32 + nb) * 16 + 8) * 16384;   // k panels
    u16* P = Pg + (size_t)z * T * T;
    float* sumz = sums + (size_t)z * T;

    const int tid = threadIdx.x, lane = tid & 63, wv = tid >> 6;  // wv 0..7
    const int wm = (wv >> 1) * 32, wn = (wv & 1) * 64;            // 4m x 2n
    const int mi = lane & 15, kq = lane >> 4;
    const int xm = mi & 7;
    const int off0 = ((2 * kq) ^ xm) * 16;       // swizzled chunk offsets
    const int off1 = ((2 * kq + 1) ^ xm) * 16;

    // staging: wave wv covers rows [wv*16, wv*16+16) of each 16KB panel
    // (2KB = 2 x 1KB contiguous loads, 16B/lane).
    const u8* gA = At + wv * 2048 + lane * 16;
    const u8* gB = Bt + wv * 2048 + lane * 16;

    floatx4 acc[2][4] = {};

    auto stageP = [&](int b) {
#if HAVE_GLL
        gload_lds16(gA,        &smem[b][wv * 2048]);
        gload_lds16(gA + 1024, &smem[b][wv * 2048 + 1024]);
        gload_lds16(gB,        &smem[b][16384 + wv * 2048]);
        gload_lds16(gB + 1024, &smem[b][16384 + wv * 2048 + 1024]);
#else
        *(uint4*)(&smem[b][wv * 2048] + lane * 16)         = *(const uint4*)gA;
        *(uint4*)(&smem[b][wv * 2048 + 1024] + lane * 16)  = *(const uint4*)(gA + 1024);
        *(uint4*)(&smem[b][16384 + wv * 2048] + lane * 16) = *(const uint4*)gB;
        *(uint4*)(&smem[b][16384 + wv * 2048 + 1024] + lane * 16) = *(const uint4*)(gB + 1024);
#endif
        gA += 16384; gB += 16384;
    };

    stageP(0);
    __syncthreads();

    for (int kp = 0; kp < 8; kp++) {
        const int cur = kp & 1;
        if (kp < 7) stageP(cur ^ 1);        // next panel flies under compute
        __builtin_amdgcn_sched_barrier(0);  // pin: staging issues before ds_reads

        const u8* Ap = &smem[cur][0];
        const u8* Bp = &smem[cur][16384];
        intx8 af[2];
#pragma unroll
        for (int i = 0; i < 2; i++) {
            const u8* p = Ap + (wm + i * 16 + mi) * 128;
            af[i] = cat8(*(const intx4*)(p + off0), *(const intx4*)(p + off1));
        }
#pragma unroll
        for (int j = 0; j < 4; j++) {
            const u8* p = Bp + (wn + j * 16 + mi) * 128;
            const intx8 bfr = cat8(*(const intx4*)(p + off0), *(const intx4*)(p + off1));
#pragma unroll
            for (int i = 0; i < 2; i++)
                acc[i][j] = __builtin_amdgcn_mfma_scale_f32_16x16x128_f8f6f4(
                    af[i], bfr, acc[i][j], 0, 0,
                    0, 0x7f7f7f7f, 0, 0x7f7f7f7f);   // unit E8M0 scales
        }
        __syncthreads();   // publishes buf cur^1; fences reads of cur
    }

    // epilogue: exp, bf16 P via LDS, fused row-sum. ct = smem[0] (32KB);
    // safe: last compute read smem[1] and the loop's final barrier passed.
    u16* ct = (u16*)&smem[0][0];
#pragma unroll
    for (int i = 0; i < 2; i++) {
#pragma unroll
        for (int r = 0; r < 4; r++) {
            const int lrow = wm + i * 16 + kq * 4 + r;
            float rs = 0.f;
#pragma unroll
            for (int j = 0; j < 4; j++) {
                float v = __expf(acc[i][j][r] * scale);
                rs += v;
                ct[lrow * 128 + wn + j * 16 + mi] = f2bf(v);
            }
            rs += __shfl_xor(rs, 1);
            rs += __shfl_xor(rs, 2);
            rs += __shfl_xor(rs, 4);
            rs += __shfl_xor(rs, 8);
            if (mi == 0) atomicAdd(&sumz[m0 + lrow], rs);
        }
    }
    __syncthreads();
#pragma unroll
    for (int it = 0; it < 4; it++) {
        const int fl = (it * 512 + tid) * 8;            // u16 elems
        const int row = fl >> 7, col = fl & 127;
        *(uint4*)(P + (size_t)(m0 + row) * T + n0 + col) = *(const uint4*)(ct + fl);
    }
}

// fp32 -> bf16, 8 elements per thread
__global__ __launch_bounds__(256) void cvt_bf16(const float* __restrict__ s,
                                                u16* __restrict__ d, int n8)
{
    int i = blockIdx.x * 256 + threadIdx.x;
    if (i >= n8) return;
    const float4* sp = (const float4*)s;
    float4 a = sp[2 * i], b = sp[2 * i + 1];
    uint4 o;
    o.x = (u32)f2bf(a.x) | ((u32)f2bf(a.y) << 16);
    o.y = (u32)f2bf(a.z) | ((u32)f2bf(a.w) << 16);
    o.z = (u32)f2bf(b.x) | ((u32)f2bf(b.y) << 16);
    o.w = (u32)f2bf(b.z) | ((u32)f2bf(b.w) << 16);
    *(uint4*)(d + 8 * i) = o;
}

__global__ void concat2(const float* __restrict__ a, const float* __restrict__ b,
                        float* __restrict__ d, int n)
{
    int i = blockIdx.x * 256 + threadIdx.x;
    if (i < n) d[i] = a[i];
    else if (i < 2 * n) d[i] = b[i - n];
}

extern "C" void kernel_launch(void* const* d_in, const int* in_sizes, int n_in,
                              void* d_out, int out_size, void* d_ws, size_t ws_size,
                              hipStream_t stream)
{
    const float* X  = (const float*)d_in[0];
    const float* Wq = (const float*)d_in[1];
    const float* bq = (const float*)d_in[2];
    const float* Wk = (const float*)d_in[3];
    const float* bk = (const float*)d_in[4];
    const float* Wv = (const float*)d_in[5];
    const float* bv = (const float*)d_in[6];
    float* out = (float*)d_out;

    const int T = 4096, NT = 4 * T; // 16384 tokens
    const long long TL = T;

    char* ws = (char*)d_ws;
    size_t off = 0;
    auto alloc = [&](size_t bytes) {
        char* p = ws + off;
        off += (bytes + 255) & ~(size_t)255;
        return p;
    };
    u16*   Wqk  = (u16*)alloc((size_t)2048 * 1024 * 2);
    u16*   Wvb  = (u16*)alloc((size_t)1024 * 1024 * 2);
    float* bqk  = (float*)alloc(2048 * 4);
    u8*    QKt  = (u8*)alloc((size_t)128 * 16 * 16384);   // fp8 tiled q|k, 32 MB
    u16*   Vt   = (u16*)alloc((size_t)1024 * NT * 2);     // V^T bf16: [v][token]
    float* sums = (float*)alloc((size_t)NT * 4);          // softmax denominators
    size_t pbase = off;
    u16*   Xb   = (u16*)alloc((size_t)NT * 1024 * 2);     // X bf16; later reused as P
    u16*   P    = Xb;

    const size_t need_batched = pbase + (size_t)4 * T * T * 2;
    const bool batched = ws_size >= need_batched;

    // --- convert inputs to bf16 ---
    cvt_bf16<<<dim3((NT * 1024 / 8 + 255) / 256), dim3(256), 0, stream>>>(X, Xb, NT * 1024 / 8);
    cvt_bf16<<<dim3(512), dim3(256), 0, stream>>>(Wq, Wqk, 1024 * 1024 / 8);
    cvt_bf16<<<dim3(512), dim3(256), 0, stream>>>(Wk, Wqk + 1024 * 1024, 1024 * 1024 / 8);
    cvt_bf16<<<dim3(512), dim3(256), 0, stream>>>(Wv, Wvb, 1024 * 1024 / 8);
    concat2<<<dim3(8), dim3(256), 0, stream>>>(bq, bk, bqk, 1024);
    hipMemsetAsync(sums, 0, (size_t)NT * 4, stream);

    // --- QK(fp8, tiled) = X * [Wq;Wk]^T + bqk : M=16384, N=2048, K=1024 ---
    gemm_bt<u8, 1, 0><<<dim3(16, 128, 1), dim3(256), 0, stream>>>(
        Xb, Wqk, QKt, 1024, 1024, 0, 1024, bqk, 0.f, 0, 0, 0, 0, 0);

    // --- V^T = Wv * X^T + bv(row) : M=1024, N=16384, K=1024 ---
    gemm_bt<u16, 2, 0><<<dim3(128, 8, 1), dim3(256), 0, stream>>>(
        Wvb, Xb, Vt, 1024, 1024, NT, 1024, bv, 0.f, 0, 0, 0, 0, 0);

    if (batched) {
        // P~ = exp(Q K^T / 32), fused row-sums; XCD-swizzled + L2 super-tiled
        gemm_fp8_scores<1><<<dim3(4096), dim3(512), 0, stream>>>(
            QKt, P, sums, 0.03125f, T);
        // out = (P~ * V) / sums ; 256^2-tile deep-pipelined kernel, 1 blk/CU
        gemm_pv256<<<dim3(256), dim3(512), 0, stream>>>(
            P, Vt, out, sums, T, NT);
    } else {
        for (int z = 0; z < 4; z++) {
            gemm_fp8_scores<0><<<dim3(32, 32, 1), dim3(512), 0, stream>>>(
                QKt + (size_t)z * 32 * 16 * 16384, P, sums + (size_t)z * T, 0.03125f, T);
            gemm_bt<float, 4, 0><<<dim3(8, 32, 1), dim3(256), 0, stream>>>(
                P, Vt + (size_t)z * T, out + (size_t)z * T * 1024,
                T, NT, 1024, T, sums + (size_t)z * T, 0.f, 0, 0, 0, 0, 0);
        }
    }
    (void)in_sizes; (void)n_in; (void)out_size;
}